// Round 5
// baseline (1417.260 us; speedup 1.0000x reference)
//
#include <hip/hip_runtime.h>
#include <math.h>

#define NB 512
#define NN 129
#define DMM 256
#define NH 8
#define HDm 32
#define TT 128

#define PI_OFF ((size_t)NB * TT * NN)

// Finite stand-in for -inf in the OUTPUT buffer only (internal math keeps -inf).
#define NEG_SENTINEL (-1.0e30f)

// ---- workspace layout (floats) ----
#define EQ_SZ ((size_t)NB * NN * DMM)          // Eq  [B][N][D]
#define V_OFF (EQ_SZ)                           // Vws [B][N][D]
#define W2_OFF (2 * EQ_SZ)                      // W2  [D][D]
#define QC_OFF (2 * EQ_SZ + (size_t)DMM * DMM)  // Qc  [B][D]

// fast tanh: 1 - 2/(e^{2x}+1). Monotone, correct saturation, ~2ulp via v_exp.
__device__ __forceinline__ float tanh_fast(float x) {
  return 1.0f - 2.0f / (__expf(2.0f * x) + 1.0f);
}

// W2[d][i] = sum_j Wk_tanh[d][j] * Wo[i][j]
__global__ __launch_bounds__(256) void w2_kernel(const float* __restrict__ Wkt,
                                                 const float* __restrict__ Wo,
                                                 float* __restrict__ W2) {
  __shared__ __align__(16) float rowL[DMM];
  int d = blockIdx.x, i = threadIdx.x;
  rowL[i] = Wkt[d * DMM + i];
  __syncthreads();
  const float4* wo4 = (const float4*)(Wo + (size_t)i * DMM);
  const float4* r4 = (const float4*)rowL;
  float acc = 0.f;
  #pragma unroll 8
  for (int jq = 0; jq < DMM / 4; ++jq) {
    float4 a = r4[jq], bq = wo4[jq];
    acc += a.x * bq.x + a.y * bq.y + a.z * bq.z + a.w * bq.w;
  }
  W2[d * DMM + i] = acc;
}

// Qc[b][j] = sum_i ctx[b][i] * Wqc[i][j]
__global__ __launch_bounds__(256) void qc_kernel(const float* __restrict__ ctx,
                                                 const float* __restrict__ Wqc,
                                                 float* __restrict__ Qc) {
  __shared__ __align__(16) float cL[DMM];
  int b = blockIdx.x, j = threadIdx.x;
  cL[j] = ctx[b * DMM + j];
  __syncthreads();
  float acc = 0.f;
  for (int i = 0; i < DMM; ++i) acc += cL[i] * Wqc[i * DMM + j];
  Qc[b * DMM + j] = acc;
}

// Eq = emb @ Wq_step[:256,:]; Vws = emb @ Wv   (64-row tiles)
__global__ __launch_bounds__(256) void eqv_kernel(const float* __restrict__ emb,
                                                  const float* __restrict__ Wqs,
                                                  const float* __restrict__ Wv,
                                                  float* __restrict__ Eq,
                                                  float* __restrict__ Vws) {
  __shared__ __align__(16) float eL[64][DMM];  // 64KB
  int j = threadIdx.x;
  size_t r0 = (size_t)blockIdx.x * 64;
  for (int k = 0; k < 64; ++k) eL[k][j] = emb[(r0 + k) * DMM + j];
  __syncthreads();
  float accE[64], accV[64];
  #pragma unroll
  for (int r = 0; r < 64; ++r) { accE[r] = 0.f; accV[r] = 0.f; }
  for (int iq = 0; iq < 64; ++iq) {
    float we[4], wv[4];
    #pragma unroll
    for (int k = 0; k < 4; ++k) {
      we[k] = Wqs[(iq * 4 + k) * DMM + j];
      wv[k] = Wv[(iq * 4 + k) * DMM + j];
    }
    #pragma unroll
    for (int r = 0; r < 64; ++r) {
      float4 e = *(const float4*)&eL[r][iq * 4];
      accE[r] += e.x * we[0] + e.y * we[1] + e.z * we[2] + e.w * we[3];
      accV[r] += e.x * wv[0] + e.y * wv[1] + e.z * wv[2] + e.w * wv[3];
    }
  }
  for (int r = 0; r < 64; ++r) {
    Eq[(r0 + r) * DMM + j] = accE[r];
    Vws[(r0 + r) * DMM + j] = accV[r];
  }
}

// One block per batch element; runs all 128 decode steps.
// Single barrier per step. R5: Eq[b] staged in LDS (kills per-step global
// gather latency); deferred softmax normalization (sum-reduce overlaps PV dot);
// shift-free lse (se chain overlaps argmax chain).
__global__ __launch_bounds__(512, 2) void decode_kernel(
    const float* __restrict__ emb, const float* __restrict__ demands,
    const float* __restrict__ Wk, const float* __restrict__ Wqs,
    const float* __restrict__ Eq, const float* __restrict__ W2,
    const float* __restrict__ Qc, const float* __restrict__ Vws,
    float* __restrict__ out) {
  extern __shared__ float sm[];
  float* K128L = sm;           // 256
  float* T128L = sm + 256;     // 256
  float* V128L = sm + 512;     // 256
  float* demL = sm + 768;      // 132 -> pad to 904
  float* SCR = sm + 904;       // [129][257]: embL during init, EqL during steps
  float* SCR2 = SCR + 33156;   // init: WkT[8][256]+W2T[8][256]; steps: views
  // init views
  float* embL = SCR;
  float* WkT = SCR2;                   // [8][256]
  float* W2T = SCR2 + 2048;            // [8][256]
  // step views (alias the WkT/W2T region, 3680 <= 4096 floats)
  float* EqL = SCR;                    // [129][257]
  float* qL = SCR2;                    // 256   (per-wave 32-slices)
  float* pm = SCR2 + 256;              // [8][132] per-wave private, UNNORMALIZED e
  float* attnL = SCR2 + 1312;          // 256   (per-wave 32-slices)
  float* ypd = SCR2 + 1568;            // 2 x [8][132] double-buffered

  const int tid = threadIdx.x;
  const int b = blockIdx.x;
  const int w = tid >> 6;        // wave = head
  const int l = tid & 63;
  const int dv = l & 31, h2 = l >> 5;

  const float* embB = emb + (size_t)b * NN * DMM;

  // stage emb[b] into LDS, stride 257 (conflict-free lane-varying row reads)
  for (int idx = tid; idx < NN * DMM; idx += 512) {
    int r = idx >> 8, c = idx & 255;
    embL[r * 257 + c] = embB[idx];
  }
  if (tid < 132) demL[tid] = (tid < NN) ? demands[b * NN + tid] : 0.f;
  __syncthreads();

  // node-128 rows (K, Kt2 computed; V loaded)
  if (tid < 256) {
    float a0 = 0.f, a1 = 0.f;
    for (int i = 0; i < DMM; ++i) {
      float e = embL[128 * 257 + i];
      a0 += e * Wk[i * DMM + tid];
      a1 += e * W2[i * DMM + tid];
    }
    K128L[tid] = a0;
    T128L[tid] = a1;
    V128L[tid] = Vws[((size_t)b * NN + 128) * DMM + tid];
  }

  // build K and Kt2 register tiles: rows (l, l+64), cols = head slice w*32..+31
  float Kr0[HDm], Kr1[HDm], Tr0[HDm], Tr1[HDm];
  #pragma unroll
  for (int d = 0; d < HDm; ++d) { Kr0[d] = 0.f; Kr1[d] = 0.f; Tr0[d] = 0.f; Tr1[d] = 0.f; }
  for (int it = 0; it < 32; ++it) {
    __syncthreads();
    for (int idx = tid; idx < 2048; idx += 512) {
      WkT[idx] = Wk[it * 2048 + idx];
      W2T[idx] = W2[it * 2048 + idx];
    }
    __syncthreads();
    for (int i = 0; i < 8; ++i) {
      float e0 = embL[l * 257 + it * 8 + i];
      float e1 = embL[(l + 64) * 257 + it * 8 + i];
      const float4* wk4 = (const float4*)(WkT + i * DMM + w * HDm);
      const float4* w24 = (const float4*)(W2T + i * DMM + w * HDm);
      #pragma unroll
      for (int c = 0; c < 8; ++c) {
        float4 kv = wk4[c], tv = w24[c];
        Kr0[4*c+0] += e0 * kv.x; Kr0[4*c+1] += e0 * kv.y; Kr0[4*c+2] += e0 * kv.z; Kr0[4*c+3] += e0 * kv.w;
        Kr1[4*c+0] += e1 * kv.x; Kr1[4*c+1] += e1 * kv.y; Kr1[4*c+2] += e1 * kv.z; Kr1[4*c+3] += e1 * kv.w;
        Tr0[4*c+0] += e0 * tv.x; Tr0[4*c+1] += e0 * tv.y; Tr0[4*c+2] += e0 * tv.z; Tr0[4*c+3] += e0 * tv.w;
        Tr1[4*c+0] += e1 * tv.x; Tr1[4*c+1] += e1 * tv.y; Tr1[4*c+2] += e1 * tv.z; Tr1[4*c+3] += e1 * tv.w;
      }
    }
  }

  // V registers: lane (dv,h2) holds V[n = h2*64 + j][w*32 + dv], j = 0..63
  float Vr[64];
  {
    const float* vb = Vws + ((size_t)b * NN + h2 * 64) * DMM + w * HDm + dv;
    #pragma unroll
    for (int jj = 0; jj < 64; ++jj) Vr[jj] = vb[(size_t)jj * DMM];
  }

  // per-lane q components for dim d = w*32 + dv (duplicated across h2 halves)
  float qcR = Qc[b * DMM + w * HDm + dv];
  float wqR = Wqs[256 * DMM + w * HDm + dv];
  float eqR = Eq[((size_t)b * NN + 0) * DMM + w * HDm + dv];

  // ---- overwrite embL with Eq[b] (per-step gather becomes an LDS read) ----
  __syncthreads();  // all waves done reading embL/WkT
  {
    const float* EqB = Eq + (size_t)b * NN * DMM;
    for (int idx = tid; idx < NN * DMM; idx += 512) {
      int r = idx >> 8, c = idx & 255;
      EqL[r * 257 + c] = EqB[idx];
    }
  }

  float used = 0.f;
  int vis0 = 0, vis1 = 0, vis128 = 0;  // per-lane visited flags (nodes l, l+64, 128)
  __syncthreads();

  float* outB = out + (size_t)b * TT * NN;

  for (int t = 0; t < TT; ++t) {
    // ---- P1: q slice (intra-wave; lanes 0..31 write, all read) ----
    float qd = qcR + eqR + (1.0f - used) * wqR;
    if (l < 32) qL[w * HDm + l] = qd;

    // ---- P2: compat (intra-wave; no max-shift, no normalization yet) ----
    float s0, s1, s2;
    {
      const float4* q4 = (const float4*)(qL + w * HDm);
      const float4* k4 = (const float4*)(K128L + w * HDm);
      float a0 = 0.f, a1 = 0.f, a2 = 0.f, a3 = 0.f;
      float b0 = 0.f, b1 = 0.f, b2 = 0.f, b3 = 0.f;
      float c0 = 0.f, c1 = 0.f, c2 = 0.f, c3 = 0.f;
      #pragma unroll
      for (int c = 0; c < 8; ++c) {
        float4 q = q4[c], k = k4[c];
        a0 += q.x * Kr0[4*c];   a1 += q.y * Kr0[4*c+1];
        a2 += q.z * Kr0[4*c+2]; a3 += q.w * Kr0[4*c+3];
        b0 += q.x * Kr1[4*c];   b1 += q.y * Kr1[4*c+1];
        b2 += q.z * Kr1[4*c+2]; b3 += q.w * Kr1[4*c+3];
        c0 += q.x * k.x; c1 += q.y * k.y; c2 += q.z * k.z; c3 += q.w * k.w;
      }
      s0 = ((a0 + a1) + (a2 + a3)) * 0.03125f;
      s1 = ((b0 + b1) + (b2 + b3)) * 0.03125f;
      s2 = ((c0 + c1) + (c2 + c3)) * 0.03125f;
    }
    if (vis0) s0 = -INFINITY;
    if (vis1) s1 = -INFINITY;
    // exp without max-shift: |s| is O(1..10) by problem construction, f32-safe.
    float e0 = __expf(s0), e1 = __expf(s1);
    float e2 = (l == 0 && !vis128) ? __expf(s2) : 0.f;
    // write UNNORMALIZED e; sum-reduce overlaps the PV dot below
    pm[w * 132 + l] = e0;
    pm[w * 132 + 64 + l] = e1;
    if (l == 0) pm[w * 132 + 128] = e2;
    float psum = e0 + e1 + e2;

    // ---- P3: attn_unnorm[w][dv] = sum_n e[w][n] * V[n][w*32+dv] ----
    float acc;
    {
      const float4* pr = (const float4*)(pm + w * 132 + h2 * 64);
      float a0 = 0.f, a1 = 0.f, a2 = 0.f, a3 = 0.f;
      #pragma unroll
      for (int jq = 0; jq < 16; ++jq) {
        float4 p4 = pr[jq];
        a0 += p4.x * Vr[4*jq];   a1 += p4.y * Vr[4*jq+1];
        a2 += p4.z * Vr[4*jq+2]; a3 += p4.w * Vr[4*jq+3];
      }
      acc = (a0 + a1) + (a2 + a3);
    }
    if (h2 == 0) acc += pm[w * 132 + 128] * V128L[w * HDm + dv];
    // sum-reduce (independent of the dot; chains overlap in issue)
    #pragma unroll
    for (int o = 32; o > 0; o >>= 1) psum += __shfl_xor(psum, o);
    acc += __shfl_xor(acc, 32);
    acc *= (1.0f / psum);
    if (l < 32) attnL[w * HDm + l] = acc;

    // ---- P4: per-head logit partials (intra-wave) + ypart writes ----
    float* ypb = ypd + (t & 1) * 1056;
    float y0, y1;
    {
      const float4* a4 = (const float4*)(attnL + w * HDm);
      float a0 = 0.f, a1 = 0.f, a2 = 0.f, a3 = 0.f;
      float b0 = 0.f, b1 = 0.f, b2 = 0.f, b3 = 0.f;
      #pragma unroll
      for (int c = 0; c < 8; ++c) {
        float4 a = a4[c];
        a0 += a.x * Tr0[4*c];   a1 += a.y * Tr0[4*c+1];
        a2 += a.z * Tr0[4*c+2]; a3 += a.w * Tr0[4*c+3];
        b0 += a.x * Tr1[4*c];   b1 += a.y * Tr1[4*c+1];
        b2 += a.z * Tr1[4*c+2]; b3 += a.w * Tr1[4*c+3];
      }
      y0 = (a0 + a1) + (a2 + a3);
      y1 = (b0 + b1) + (b2 + b3);
    }
    ypb[w * 132 + l] = y0;
    ypb[w * 132 + 64 + l] = y1;
    // node-128 partial for this head: attn[w][:] . T128[w*32..]
    {
      float yy = 0.f;
      if (l < 8) {
        float4 a = ((const float4*)(attnL + w * HDm))[l];
        float4 tq = ((const float4*)(T128L + w * HDm))[l];
        yy = a.x * tq.x + a.y * tq.y + a.z * tq.z + a.w * tq.w;
      }
      yy += __shfl_xor(yy, 4);
      yy += __shfl_xor(yy, 2);
      yy += __shfl_xor(yy, 1);
      if (l == 0) ypb[w * 132 + 128] = yy;
    }

    __syncthreads();  // the ONLY barrier per step

    // ---- P5 common (all waves): raw sums, raw argmax, sel, prefetch ----
    const float* yp = ypd + (t & 1) * 1056;
    float ya = 0.f, yb = 0.f, ys = 0.f;
    #pragma unroll
    for (int ww = 0; ww < 8; ++ww) {
      ya += yp[ww * 132 + l];
      yb += yp[ww * 132 + 64 + l];
      ys += yp[ww * 132 + 128];  // broadcast read, free
    }
    float ra = vis0 ? -INFINITY : ya;
    float rb = vis1 ? -INFINITY : yb;
    float rc = (l == 0 && !vis128) ? ys : -INFINITY;

    // argmax on RAW masked logits (tanh monotone => same argmax as log_p)
    float bv = ra;
    int bi = l;
    if (rb > bv) { bv = rb; bi = l + 64; }
    if (rc > bv) { bv = rc; bi = 128; }
    #pragma unroll
    for (int o = 32; o > 0; o >>= 1) {
      float ov = __shfl_xor(bv, o);
      int oi = __shfl_xor(bi, o);
      if (ov > bv || (ov == bv && oi < bi)) { bv = ov; bi = oi; }
    }
    const int sel = bi;  // identical in every wave
    float eqNew = EqL[sel * 257 + w * HDm + dv];  // LDS broadcast-row read
    float dmv = demL[sel];

    // ---- P5 writer (wave 0 only): tanh, shift-free lse, stores ----
    if (w == 0) {
      float ta = vis0 ? -INFINITY : 10.f * tanh_fast(ya * 0.0625f);
      float tb = vis1 ? -INFINITY : 10.f * tanh_fast(yb * 0.0625f);
      float tc = (l == 0 && !vis128) ? 10.f * tanh_fast(ys * 0.0625f) : -INFINITY;
      // |t| <= 10 so exp is overflow-safe without max-shift; se-chain is
      // independent of the argmax chain above (they overlap in issue).
      float ea = __expf(ta), eb = __expf(tb);
      float ec = (l == 0 && !vis128) ? __expf(tc) : 0.f;
      float se = ea + eb + ec;
      #pragma unroll
      for (int o = 32; o > 0; o >>= 1) se += __shfl_xor(se, o);
      float lse = __logf(se);
      float* op = outB + (size_t)t * NN;
      op[l] = fmaxf(ta - lse, NEG_SENTINEL);
      op[l + 64] = fmaxf(tb - lse, NEG_SENTINEL);
      if (l == 0) {
        op[128] = fmaxf(tc - lse, NEG_SENTINEL);
        out[PI_OFF + (size_t)b * TT + t] = (float)sel;
      }
    }

    // ---- P6: state update (all per-lane registers) ----
    used = (sel == 0) ? 0.f : used + dmv;
    if (sel == l && sel != 0) vis0 = 1;
    if (sel == l + 64) vis1 = 1;
    if (sel == 128) vis128 = 1;
    eqR = eqNew;
  }
}

extern "C" void kernel_launch(void* const* d_in, const int* in_sizes, int n_in,
                              void* d_out, int out_size, void* d_ws, size_t ws_size,
                              hipStream_t stream) {
  const float* emb = (const float*)d_in[0];
  const float* ctx = (const float*)d_in[1];
  const float* dem = (const float*)d_in[2];
  const float* Wqc = (const float*)d_in[3];
  const float* Wqs = (const float*)d_in[4];
  const float* Wk = (const float*)d_in[5];
  const float* Wkt = (const float*)d_in[6];
  const float* Wv = (const float*)d_in[7];
  const float* Wo = (const float*)d_in[8];
  float* out = (float*)d_out;
  float* ws = (float*)d_ws;

  float* Eq = ws;
  float* Vws = ws + V_OFF;
  float* W2 = ws + W2_OFF;
  float* Qc = ws + QC_OFF;

  w2_kernel<<<dim3(DMM), dim3(DMM), 0, stream>>>(Wkt, Wo, W2);
  qc_kernel<<<dim3(NB), dim3(DMM), 0, stream>>>(ctx, Wqc, Qc);
  eqv_kernel<<<dim3((NB * NN) / 64), dim3(256), 0, stream>>>(emb, Wqs, Wv, Eq, Vws);

  const int SMEM = 38156 * 4;  // 152,624 B dynamic LDS
  hipFuncSetAttribute(reinterpret_cast<const void*>(decode_kernel),
                      hipFuncAttributeMaxDynamicSharedMemorySize, SMEM);
  decode_kernel<<<dim3(NB), dim3(512), SMEM, stream>>>(emb, dem, Wk, Wqs, Eq, W2, Qc,
                                                       Vws, out);
}

// Round 6
// 1351.906 us; speedup vs baseline: 1.0483x; 1.0483x over previous
//
#include <hip/hip_runtime.h>
#include <math.h>

#define NB 512
#define NN 129
#define DMM 256
#define NH 8
#define HDm 32
#define TT 128

#define PI_OFF ((size_t)NB * TT * NN)

// Finite stand-in for -inf in the OUTPUT buffer only (internal math keeps -inf).
#define NEG_SENTINEL (-1.0e30f)

// ---- workspace layout (floats) ----
#define EQ_SZ ((size_t)NB * NN * DMM)          // Eq  [B][N][D]
#define V_OFF (EQ_SZ)                           // Vws [B][N][D]
#define W2_OFF (2 * EQ_SZ)                      // W2  [D][D]
#define QC_OFF (2 * EQ_SZ + (size_t)DMM * DMM)  // Qc  [B][D]

// fast tanh: 1 - 2/(e^{2x}+1). Monotone, correct saturation, ~2ulp via v_exp.
__device__ __forceinline__ float tanh_fast(float x) {
  return 1.0f - 2.0f / (__expf(2.0f * x) + 1.0f);
}

// W2[d][i] = sum_j Wk_tanh[d][j] * Wo[i][j]
__global__ __launch_bounds__(256) void w2_kernel(const float* __restrict__ Wkt,
                                                 const float* __restrict__ Wo,
                                                 float* __restrict__ W2) {
  __shared__ __align__(16) float rowL[DMM];
  int d = blockIdx.x, i = threadIdx.x;
  rowL[i] = Wkt[d * DMM + i];
  __syncthreads();
  const float4* wo4 = (const float4*)(Wo + (size_t)i * DMM);
  const float4* r4 = (const float4*)rowL;
  float acc = 0.f;
  #pragma unroll 8
  for (int jq = 0; jq < DMM / 4; ++jq) {
    float4 a = r4[jq], bq = wo4[jq];
    acc += a.x * bq.x + a.y * bq.y + a.z * bq.z + a.w * bq.w;
  }
  W2[d * DMM + i] = acc;
}

// Qc[b][j] = sum_i ctx[b][i] * Wqc[i][j]
__global__ __launch_bounds__(256) void qc_kernel(const float* __restrict__ ctx,
                                                 const float* __restrict__ Wqc,
                                                 float* __restrict__ Qc) {
  __shared__ __align__(16) float cL[DMM];
  int b = blockIdx.x, j = threadIdx.x;
  cL[j] = ctx[b * DMM + j];
  __syncthreads();
  float acc = 0.f;
  for (int i = 0; i < DMM; ++i) acc += cL[i] * Wqc[i * DMM + j];
  Qc[b * DMM + j] = acc;
}

// Eq = emb @ Wq_step[:256,:]; Vws = emb @ Wv   (64-row tiles)
__global__ __launch_bounds__(256) void eqv_kernel(const float* __restrict__ emb,
                                                  const float* __restrict__ Wqs,
                                                  const float* __restrict__ Wv,
                                                  float* __restrict__ Eq,
                                                  float* __restrict__ Vws) {
  __shared__ __align__(16) float eL[64][DMM];  // 64KB
  int j = threadIdx.x;
  size_t r0 = (size_t)blockIdx.x * 64;
  for (int k = 0; k < 64; ++k) eL[k][j] = emb[(r0 + k) * DMM + j];
  __syncthreads();
  float accE[64], accV[64];
  #pragma unroll
  for (int r = 0; r < 64; ++r) { accE[r] = 0.f; accV[r] = 0.f; }
  for (int iq = 0; iq < 64; ++iq) {
    float we[4], wv[4];
    #pragma unroll
    for (int k = 0; k < 4; ++k) {
      we[k] = Wqs[(iq * 4 + k) * DMM + j];
      wv[k] = Wv[(iq * 4 + k) * DMM + j];
    }
    #pragma unroll
    for (int r = 0; r < 64; ++r) {
      float4 e = *(const float4*)&eL[r][iq * 4];
      accE[r] += e.x * we[0] + e.y * we[1] + e.z * we[2] + e.w * we[3];
      accV[r] += e.x * wv[0] + e.y * wv[1] + e.z * wv[2] + e.w * wv[3];
    }
  }
  for (int r = 0; r < 64; ++r) {
    Eq[(r0 + r) * DMM + j] = accE[r];
    Vws[(r0 + r) * DMM + j] = accV[r];
  }
}

// One block per batch element; runs all 128 decode steps.
// Single barrier per step. R6: output tail (tanh/lse/stores) software-pipelined
// one step behind and spread across all 8 waves; psum normalization deferred to
// the P4 outputs; ballot-based argmax.
__global__ __launch_bounds__(512, 2) void decode_kernel(
    const float* __restrict__ emb, const float* __restrict__ demands,
    const float* __restrict__ Wk, const float* __restrict__ Wqs,
    const float* __restrict__ Eq, const float* __restrict__ W2,
    const float* __restrict__ Qc, const float* __restrict__ Vws,
    float* __restrict__ out) {
  extern __shared__ float sm[];
  float* K128L = sm;           // 256
  float* T128L = sm + 256;     // 256
  float* V128L = sm + 512;     // 256
  float* demL = sm + 768;      // 132 -> pad to 904
  float* SCR = sm + 904;       // init: embL [129][257]
  float* SCR2 = SCR + 33156;   // init: WkT/W2T; steps: views
  // init views
  float* embL = SCR;
  float* WkT = SCR2;                   // [8][256]
  float* W2T = SCR2 + 2048;            // [8][256]
  // step views (alias the WkT/W2T region, 3680 <= 4096 floats)
  float* qL = SCR2;                    // 256   (per-wave 32-slices)
  float* pm = SCR2 + 256;              // [8][132] per-wave private, UNNORMALIZED e
  float* attnL = SCR2 + 1312;          // 256   (per-wave 32-slices, UNNORMALIZED)
  float* ypd = SCR2 + 1568;            // 2 x [8][132] double-buffered

  const int tid = threadIdx.x;
  const int b = blockIdx.x;
  const int w = tid >> 6;        // wave = head
  const int l = tid & 63;
  const int dv = l & 31, h2 = l >> 5;

  const float* embB = emb + (size_t)b * NN * DMM;

  // stage emb[b] into LDS, stride 257 (conflict-free lane-varying row reads)
  for (int idx = tid; idx < NN * DMM; idx += 512) {
    int r = idx >> 8, c = idx & 255;
    embL[r * 257 + c] = embB[idx];
  }
  if (tid < 132) demL[tid] = (tid < NN) ? demands[b * NN + tid] : 0.f;
  __syncthreads();

  // node-128 rows (K, Kt2 computed; V loaded)
  if (tid < 256) {
    float a0 = 0.f, a1 = 0.f;
    for (int i = 0; i < DMM; ++i) {
      float e = embL[128 * 257 + i];
      a0 += e * Wk[i * DMM + tid];
      a1 += e * W2[i * DMM + tid];
    }
    K128L[tid] = a0;
    T128L[tid] = a1;
    V128L[tid] = Vws[((size_t)b * NN + 128) * DMM + tid];
  }

  // build K and Kt2 register tiles: rows (l, l+64), cols = head slice w*32..+31
  float Kr0[HDm], Kr1[HDm], Tr0[HDm], Tr1[HDm];
  #pragma unroll
  for (int d = 0; d < HDm; ++d) { Kr0[d] = 0.f; Kr1[d] = 0.f; Tr0[d] = 0.f; Tr1[d] = 0.f; }
  for (int it = 0; it < 32; ++it) {
    __syncthreads();
    for (int idx = tid; idx < 2048; idx += 512) {
      WkT[idx] = Wk[it * 2048 + idx];
      W2T[idx] = W2[it * 2048 + idx];
    }
    __syncthreads();
    for (int i = 0; i < 8; ++i) {
      float e0 = embL[l * 257 + it * 8 + i];
      float e1 = embL[(l + 64) * 257 + it * 8 + i];
      const float4* wk4 = (const float4*)(WkT + i * DMM + w * HDm);
      const float4* w24 = (const float4*)(W2T + i * DMM + w * HDm);
      #pragma unroll
      for (int c = 0; c < 8; ++c) {
        float4 kv = wk4[c], tv = w24[c];
        Kr0[4*c+0] += e0 * kv.x; Kr0[4*c+1] += e0 * kv.y; Kr0[4*c+2] += e0 * kv.z; Kr0[4*c+3] += e0 * kv.w;
        Kr1[4*c+0] += e1 * kv.x; Kr1[4*c+1] += e1 * kv.y; Kr1[4*c+2] += e1 * kv.z; Kr1[4*c+3] += e1 * kv.w;
        Tr0[4*c+0] += e0 * tv.x; Tr0[4*c+1] += e0 * tv.y; Tr0[4*c+2] += e0 * tv.z; Tr0[4*c+3] += e0 * tv.w;
        Tr1[4*c+0] += e1 * tv.x; Tr1[4*c+1] += e1 * tv.y; Tr1[4*c+2] += e1 * tv.z; Tr1[4*c+3] += e1 * tv.w;
      }
    }
  }

  // V registers: lane (dv,h2) holds V[n = h2*64 + j][w*32 + dv], j = 0..63
  float Vr[64];
  {
    const float* vb = Vws + ((size_t)b * NN + h2 * 64) * DMM + w * HDm + dv;
    #pragma unroll
    for (int jj = 0; jj < 64; ++jj) Vr[jj] = vb[(size_t)jj * DMM];
  }

  // per-lane q components for dim d = w*32 + dv (duplicated across h2 halves)
  float qcR = Qc[b * DMM + w * HDm + dv];
  float wqR = Wqs[256 * DMM + w * HDm + dv];
  float eqR = Eq[((size_t)b * NN + 0) * DMM + w * HDm + dv];

  float used = 0.f;
  int vis0 = 0, vis1 = 0, vis128 = 0;  // per-lane visited flags (nodes l, l+64, 128)
  // pipelined output state (logits of step t-1, already masked)
  float pa = 0.f, pb = 0.f, pc = 0.f;
  __syncthreads();

  float* outB = out + (size_t)b * TT * NN;

  for (int t = 0; t < TT; ++t) {
    // ---- P1: q slice (intra-wave; lanes 0..31 write, all read) ----
    float qd = qcR + eqR + (1.0f - used) * wqR;
    if (l < 32) qL[w * HDm + l] = qd;

    // ---- deferred output tail for step t-1 (all waves, redundant lse) ----
    // se-chain and stores overlap P2-P4 compute; stores drain long before the
    // barrier. Each wave stores a 16-element slice.
    if (t > 0) {
      float ta = (pa == -INFINITY) ? -INFINITY : 10.f * tanh_fast(pa * 0.0625f);
      float tb = (pb == -INFINITY) ? -INFINITY : 10.f * tanh_fast(pb * 0.0625f);
      float tc = (l == 0 && pc != -INFINITY) ? 10.f * tanh_fast(pc * 0.0625f)
                                             : -INFINITY;
      // |t| <= 10: shift-free lse is overflow-safe.
      float ea = __expf(ta), eb = __expf(tb);
      float ec = (l == 0) ? __expf(tc) : 0.f;
      float se = ea + eb + ec;
      #pragma unroll
      for (int o = 32; o > 0; o >>= 1) se += __shfl_xor(se, o);
      float lse = __logf(se);
      float* op = outB + (size_t)(t - 1) * NN;
      if (w < 4) {
        if ((l >> 4) == w) op[l] = fmaxf(ta - lse, NEG_SENTINEL);
      } else {
        if ((l >> 4) == w - 4) op[l + 64] = fmaxf(tb - lse, NEG_SENTINEL);
      }
      if (w == 0 && l == 0) op[128] = fmaxf(tc - lse, NEG_SENTINEL);
    }

    // ---- P2: compat (intra-wave; no max-shift, unnormalized e) ----
    float s0, s1, s2;
    {
      const float4* q4 = (const float4*)(qL + w * HDm);
      const float4* k4 = (const float4*)(K128L + w * HDm);
      float a0 = 0.f, a1 = 0.f, a2 = 0.f, a3 = 0.f;
      float b0 = 0.f, b1 = 0.f, b2 = 0.f, b3 = 0.f;
      float c0 = 0.f, c1 = 0.f, c2 = 0.f, c3 = 0.f;
      #pragma unroll
      for (int c = 0; c < 8; ++c) {
        float4 q = q4[c], k = k4[c];
        a0 += q.x * Kr0[4*c];   a1 += q.y * Kr0[4*c+1];
        a2 += q.z * Kr0[4*c+2]; a3 += q.w * Kr0[4*c+3];
        b0 += q.x * Kr1[4*c];   b1 += q.y * Kr1[4*c+1];
        b2 += q.z * Kr1[4*c+2]; b3 += q.w * Kr1[4*c+3];
        c0 += q.x * k.x; c1 += q.y * k.y; c2 += q.z * k.z; c3 += q.w * k.w;
      }
      s0 = ((a0 + a1) + (a2 + a3)) * 0.03125f;
      s1 = ((b0 + b1) + (b2 + b3)) * 0.03125f;
      s2 = ((c0 + c1) + (c2 + c3)) * 0.03125f;
    }
    if (vis0) s0 = -INFINITY;
    if (vis1) s1 = -INFINITY;
    float e0 = __expf(s0), e1 = __expf(s1);
    float e2 = (l == 0 && !vis128) ? __expf(s2) : 0.f;
    pm[w * 132 + l] = e0;
    pm[w * 132 + 64 + l] = e1;
    if (l == 0) pm[w * 132 + 128] = e2;
    float psum = e0 + e1 + e2;

    // ---- P3: attn_unnorm[w][dv] = sum_n e[w][n] * V[n][w*32+dv] ----
    float acc;
    {
      const float4* pr = (const float4*)(pm + w * 132 + h2 * 64);
      float a0 = 0.f, a1 = 0.f, a2 = 0.f, a3 = 0.f;
      #pragma unroll
      for (int jq = 0; jq < 16; ++jq) {
        float4 p4 = pr[jq];
        a0 += p4.x * Vr[4*jq];   a1 += p4.y * Vr[4*jq+1];
        a2 += p4.z * Vr[4*jq+2]; a3 += p4.w * Vr[4*jq+3];
      }
      acc = (a0 + a1) + (a2 + a3);
    }
    if (h2 == 0) acc += pm[w * 132 + 128] * V128L[w * HDm + dv];
    acc += __shfl_xor(acc, 32);
    if (l < 32) attnL[w * HDm + l] = acc;  // UNNORMALIZED
    // psum reduce only needs to finish by end of P4 (off the P2->P3 chain)
    #pragma unroll
    for (int o = 32; o > 0; o >>= 1) psum += __shfl_xor(psum, o);
    float inv = 1.0f / psum;

    // ---- P4: per-head logit partials; normalization applied HERE ----
    float* ypb = ypd + (t & 1) * 1056;
    float y0, y1;
    {
      const float4* a4 = (const float4*)(attnL + w * HDm);
      float a0 = 0.f, a1 = 0.f, a2 = 0.f, a3 = 0.f;
      float b0 = 0.f, b1 = 0.f, b2 = 0.f, b3 = 0.f;
      #pragma unroll
      for (int c = 0; c < 8; ++c) {
        float4 a = a4[c];
        a0 += a.x * Tr0[4*c];   a1 += a.y * Tr0[4*c+1];
        a2 += a.z * Tr0[4*c+2]; a3 += a.w * Tr0[4*c+3];
        b0 += a.x * Tr1[4*c];   b1 += a.y * Tr1[4*c+1];
        b2 += a.z * Tr1[4*c+2]; b3 += a.w * Tr1[4*c+3];
      }
      y0 = ((a0 + a1) + (a2 + a3)) * inv;
      y1 = ((b0 + b1) + (b2 + b3)) * inv;
    }
    ypb[w * 132 + l] = y0;
    ypb[w * 132 + 64 + l] = y1;
    // node-128 partial for this head: attn[w][:] . T128[w*32..]
    {
      float yy = 0.f;
      if (l < 8) {
        float4 a = ((const float4*)(attnL + w * HDm))[l];
        float4 tq = ((const float4*)(T128L + w * HDm))[l];
        yy = a.x * tq.x + a.y * tq.y + a.z * tq.z + a.w * tq.w;
      }
      yy += __shfl_xor(yy, 4);
      yy += __shfl_xor(yy, 2);
      yy += __shfl_xor(yy, 1);
      if (l == 0) ypb[w * 132 + 128] = yy * inv;
    }

    __syncthreads();  // the ONLY barrier per step

    // ---- P5 (all waves): raw sums, masks, ballot argmax, prefetch ----
    const float* yp = ypd + (t & 1) * 1056;
    float ya = 0.f, yb = 0.f, ys = 0.f;
    #pragma unroll
    for (int ww = 0; ww < 8; ++ww) {
      ya += yp[ww * 132 + l];
      yb += yp[ww * 132 + 64 + l];
      ys += yp[ww * 132 + 128];  // broadcast read, free
    }
    float ra = vis0 ? -INFINITY : ya;
    float rb = vis1 ? -INFINITY : yb;
    float rc = (l == 0 && !vis128) ? ys : -INFINITY;

    // max via fmax-only chain, index via ballot (first-index tie-break)
    float mx = fmaxf(fmaxf(ra, rb), rc);
    #pragma unroll
    for (int o = 32; o > 0; o >>= 1) mx = fmaxf(mx, __shfl_xor(mx, o));
    unsigned long long ba = __ballot(ra == mx);
    unsigned long long bb = __ballot(rb == mx);
    int sel = ba ? (__ffsll((long long)ba) - 1)
                 : (bb ? 64 + (__ffsll((long long)bb) - 1) : 128);

    float eqNew = Eq[((size_t)b * NN + sel) * DMM + w * HDm + dv];
    float dmv = demL[sel];
    if (w == 0 && l == 0) out[PI_OFF + (size_t)b * TT + t] = (float)sel;

    // save masked logits for the pipelined output tail (next iteration)
    pa = ra; pb = rb; pc = rc;

    // ---- P6: state update (all per-lane registers) ----
    used = (sel == 0) ? 0.f : used + dmv;
    if (sel == l && sel != 0) vis0 = 1;
    if (sel == l + 64) vis1 = 1;
    if (sel == 128) vis128 = 1;
    eqR = eqNew;
  }

  // ---- final deferred output tail (step TT-1) ----
  {
    float ta = (pa == -INFINITY) ? -INFINITY : 10.f * tanh_fast(pa * 0.0625f);
    float tb = (pb == -INFINITY) ? -INFINITY : 10.f * tanh_fast(pb * 0.0625f);
    float tc = (l == 0 && pc != -INFINITY) ? 10.f * tanh_fast(pc * 0.0625f)
                                           : -INFINITY;
    float ea = __expf(ta), eb = __expf(tb);
    float ec = (l == 0) ? __expf(tc) : 0.f;
    float se = ea + eb + ec;
    #pragma unroll
    for (int o = 32; o > 0; o >>= 1) se += __shfl_xor(se, o);
    float lse = __logf(se);
    float* op = outB + (size_t)(TT - 1) * NN;
    if (w < 4) {
      if ((l >> 4) == w) op[l] = fmaxf(ta - lse, NEG_SENTINEL);
    } else {
      if ((l >> 4) == w - 4) op[l + 64] = fmaxf(tb - lse, NEG_SENTINEL);
    }
    if (w == 0 && l == 0) op[128] = fmaxf(tc - lse, NEG_SENTINEL);
  }
}

extern "C" void kernel_launch(void* const* d_in, const int* in_sizes, int n_in,
                              void* d_out, int out_size, void* d_ws, size_t ws_size,
                              hipStream_t stream) {
  const float* emb = (const float*)d_in[0];
  const float* ctx = (const float*)d_in[1];
  const float* dem = (const float*)d_in[2];
  const float* Wqc = (const float*)d_in[3];
  const float* Wqs = (const float*)d_in[4];
  const float* Wk = (const float*)d_in[5];
  const float* Wkt = (const float*)d_in[6];
  const float* Wv = (const float*)d_in[7];
  const float* Wo = (const float*)d_in[8];
  float* out = (float*)d_out;
  float* ws = (float*)d_ws;

  float* Eq = ws;
  float* Vws = ws + V_OFF;
  float* W2 = ws + W2_OFF;
  float* Qc = ws + QC_OFF;

  w2_kernel<<<dim3(DMM), dim3(DMM), 0, stream>>>(Wkt, Wo, W2);
  qc_kernel<<<dim3(NB), dim3(DMM), 0, stream>>>(ctx, Wqc, Qc);
  eqv_kernel<<<dim3((NB * NN) / 64), dim3(256), 0, stream>>>(emb, Wqs, Wv, Eq, Vws);

  const int SMEM = 38156 * 4;  // 152,624 B dynamic LDS
  hipFuncSetAttribute(reinterpret_cast<const void*>(decode_kernel),
                      hipFuncAttributeMaxDynamicSharedMemorySize, SMEM);
  decode_kernel<<<dim3(NB), dim3(512), SMEM, stream>>>(emb, dem, Wk, Wqs, Eq, W2, Qc,
                                                       Vws, out);
}